// Round 5
// baseline (309.998 us; speedup 1.0000x reference)
//
#include <hip/hip_runtime.h>
#include <cstddef>
#include <cstdint>

// ---------------------------------------------------------------------------
// MultiHeadRelativeAttention (music-transformer skew), B=4 H=16 S=1024 hd=64
// Inputs/outputs f32; internal bf16 MFMA.
// R14 == R13 resubmit (container-level infra failure, no kernel verdict).
// Register-resident rel band: skew diagonal is a within-quad lane rotation:
// slot(ii=row0+r, jj=16c+ln) = 16(4t+c) + (15-4quad-r) + ln from per-wave
// origin borig=base+48-16w. Band MFMA'd then kept in VGPRs: ds_bpermute
// rotation (per m,r) + carry cndmask -> column-aligned packed regs Bp[4t+c]
// (compile-time index). Deletes lPR (42.5KB LDS), 80 ds_write_b16 + 64
// scattered ds_read_u16 + 1 fence per superiter; band MFMA 20->17 groups.
// LDS 78336->35840 B -> 4 blocks/CU; launch_bounds(256,4) caps VGPR at 128.
// GEMMs: global_load_lds staging w/ XOR swizzle (R11). exp2, log2e in Wq/bq.
// Fast ws layout (u16 elems, EM=1M): WT[0,3) relb[3,4) Kp[4,8) Vt[8,12)
//   qb[12,16) kb[16,20) vb[20,24) = 48 MB. Post-attn: WoT over WT,
//   attn out over qb[12,16). d_out front half = Qp bf16 scratch.
// ---------------------------------------------------------------------------

typedef __attribute__((ext_vector_type(8))) short bf16x8;   // 8 bf16, 4 VGPRs
typedef __attribute__((ext_vector_type(4))) float f32x4;
typedef __attribute__((ext_vector_type(4))) unsigned int u32x4;

using u16 = unsigned short;
using u32 = unsigned int;

#define QSCALE (0.125f * 1.44269504089f)   // attn scale * log2(e), folded into Wq/bq

__device__ __forceinline__ f32x4 mfma16(bf16x8 a, bf16x8 b, f32x4 c) {
  return __builtin_amdgcn_mfma_f32_16x16x32_bf16(a, b, c, 0, 0, 0);
}
__device__ __forceinline__ u32 fbits(float f) {
  union { float f; u32 u; } v; v.f = f; return v.u;
}
__device__ __forceinline__ float uif(u32 u) {
  union { u32 u; float f; } v; v.u = u; return v.f;
}
// f32 -> bf16, round-half-up (tie bias negligible at this threshold)
__device__ __forceinline__ u16 f2b(float f) { return (u16)((fbits(f) + 0x8000u) >> 16); }
__device__ __forceinline__ u32 pack2(float a, float b) {
  return ((fbits(a) + 0x8000u) >> 16) | ((fbits(b) + 0x8000u) & 0xffff0000u);
}
__device__ __forceinline__ float b2f(u16 u) {
  union { u32 i; float f; } v; v.i = ((u32)u) << 16; return v.f;
}
// raw v_exp_f32 (input already in log2 domain; log2e folded into Wq)
__device__ __forceinline__ float exp2_fast(float x) {
  float r; asm("v_exp_f32 %0, %1" : "=v"(r) : "v"(x)); return r;
}
// async global->LDS, 16B per lane; LDS dest = uniform base + lane*16
__device__ __forceinline__ void gload16(const void* g, void* l) {
  __builtin_amdgcn_global_load_lds(
      (const __attribute__((address_space(1))) u32*)g,
      (__attribute__((address_space(3))) u32*)l, 16, 0, 0);
}

// ---- bulk f32 -> bf16 conversion of q,k,v ----------------------------------
__global__ __launch_bounds__(256) void cvt_qkv(
    const float* __restrict__ a0, const float* __restrict__ a1,
    const float* __restrict__ a2, u16* __restrict__ o0,
    u16* __restrict__ o1, u16* __restrict__ o2) {
  int z = blockIdx.y;
  const float* src = (z == 0) ? a0 : (z == 1) ? a1 : a2;
  u16* dst = (z == 0) ? o0 : (z == 1) ? o1 : o2;
  size_t i = ((size_t)blockIdx.x * 256 + threadIdx.x) * 4;
  f32x4 v = *(const f32x4*)(src + i);
  uint2 pk; pk.x = pack2(v[0], v[1]); pk.y = pack2(v[2], v[3]);
  *(uint2*)(dst + i) = pk;
}

// ---- prep: z=0..2 transpose Wq/Wk/Wv (f32 -> bf16^T, Wq pre-scaled by
//      0.125*log2e); z=3 convert rel_tab f32 -> bf16 -------------------------
__global__ __launch_bounds__(256) void prep(
    const float* __restrict__ Wq, const float* __restrict__ Wk,
    const float* __restrict__ Wv, const float* __restrict__ rel,
    u16* __restrict__ WqT, u16* __restrict__ WkT, u16* __restrict__ WvT,
    u16* __restrict__ relb) {
  __shared__ __align__(16) u16 tile[64][65];
  int z = blockIdx.z;
  if (z == 3) {
    int blk = blockIdx.y * 16 + blockIdx.x;
    size_t base = (size_t)blk * 4096;
#pragma unroll
    for (int e = 0; e < 4; e++) {
      size_t idx = base + e * 1024 + threadIdx.x * 4;
      f32x4 v = *(const f32x4*)(rel + idx);
      uint2 pk; pk.x = pack2(v[0], v[1]); pk.y = pack2(v[2], v[3]);
      *(uint2*)(relb + idx) = pk;
    }
    return;
  }
  const float* W = (z == 0) ? Wq : (z == 1) ? Wk : Wv;
  u16* T = (z == 0) ? WqT : (z == 1) ? WkT : WvT;
  float sc = (z == 0) ? QSCALE : 1.0f;   // fold attn scale + log2e into Wq
  int k0 = blockIdx.x * 64, n0 = blockIdx.y * 64;
  for (int e = threadIdx.x; e < 4096; e += 256) {
    int r = e >> 6, c = e & 63;
    tile[r][c] = f2b(sc * W[(size_t)(k0 + r) * 1024 + n0 + c]);
  }
  __syncthreads();
  for (int e = threadIdx.x; e < 4096; e += 256) {
    int r = e >> 6, c = e & 63;
    T[(size_t)(n0 + r) * 1024 + k0 + c] = tile[c][r];
  }
}

// ---- transpose Wo (f32 -> bf16^T), after attn, into dead WT region ---------
__global__ __launch_bounds__(256) void transpose_wo(
    const float* __restrict__ W, u16* __restrict__ T) {
  __shared__ __align__(16) u16 tile[64][65];
  int k0 = blockIdx.x * 64, n0 = blockIdx.y * 64;
  for (int e = threadIdx.x; e < 4096; e += 256) {
    int r = e >> 6, c = e & 63;
    tile[r][c] = f2b(W[(size_t)(k0 + r) * 1024 + n0 + c]);
  }
  __syncthreads();
  for (int e = threadIdx.x; e < 4096; e += 256) {
    int r = e >> 6, c = e & 63;
    T[(size_t)(n0 + r) * 1024 + k0 + c] = tile[c][r];
  }
}

// ---- shared epilogue: acc -> C with bias, 3 layouts ------------------------
__device__ __forceinline__ void gemm_epilogue(
    f32x4 (&acc)[4][4], const float* __restrict__ bias, float bscale,
    void* __restrict__ Cv, int layout, int m0, int n0, int wr, int wc,
    int quad, int ln) {
#pragma unroll
  for (int ct = 0; ct < 4; ct++) {
    int n = n0 + wc + 16 * ct + ln;
    float bs = bscale * bias[n];
#pragma unroll
    for (int rt = 0; rt < 4; rt++) {
#pragma unroll
      for (int r = 0; r < 4; r++) {
        int m = m0 + wr + 16 * rt + quad * 4 + r;
        float v = acc[rt][ct][r] + bs;
        if (layout == 0) {
          ((float*)Cv)[(size_t)m * 1024 + n] = v;
        } else {
          int b_ = m >> 10, s = m & 1023, h = n >> 6, d = n & 63;
          size_t idx = (layout == 1)
              ? ((size_t)(b_ * 16 + h) * 1024 + s) * 64 + d
              : ((size_t)(b_ * 16 + h) * 64 + d) * 1024 + s;
          ((u16*)Cv)[idx] = f2b(v);
        }
      }
    }
  }
}

// ---- 128x128x(BK=64) GEMM, bf16 A/B staged via global_load_lds -------------
// LDS tiles are LINEAR [128][64] (gload_lds needs contiguous dest).
// Swizzle: LDS[R][8p] holds A[R][8(p ^ (R&7))]; realized by pre-swizzling the
// per-lane SOURCE column, and reading with sA = 8*((quad+(kk>>3)) ^ (ln&7)).
// Each 8-lane group then covers all 8 bank slots -> conflict-free b128 reads.
__device__ __forceinline__ void gemm_glds_body(
    const u16* __restrict__ A, const u16* __restrict__ Bt,
    const float* __restrict__ bias, float bscale, void* __restrict__ Cv,
    int layout) {
  __shared__ __align__(16) u16 As[128 * 64];
  __shared__ __align__(16) u16 Bs[128 * 64];
  int m0 = blockIdx.x * 128, n0 = blockIdx.y * 128;
  int tid = threadIdx.x;
  int w = tid >> 6, lane = tid & 63, quad = lane >> 4, ln = lane & 15;
  int wr = (w >> 1) * 64, wc = (w & 1) * 64;     // wave quadrant origin

  // staging: each wave stages 32 rows of A and B per K-step (4 instrs each);
  // lane -> row 32w+8j+(lane>>3), source col pre-swizzled
  int rowin = lane >> 3;                         // 0..7
  int swz = ((lane & 7) ^ rowin) * 8;            // u16 col offset in row

  f32x4 acc[4][4];
#pragma unroll
  for (int i = 0; i < 4; i++)
#pragma unroll
    for (int j = 0; j < 4; j++) { acc[i][j][0]=0.f; acc[i][j][1]=0.f; acc[i][j][2]=0.f; acc[i][j][3]=0.f; }

  const u16* aA = A  + (size_t)(m0 + 32 * w + rowin) * 1024 + swz;
  const u16* aB = Bt + (size_t)(n0 + 32 * w + rowin) * 1024 + swz;

  for (int k0 = 0; k0 < 1024; k0 += 64) {
#pragma unroll
    for (int j = 0; j < 4; j++) {
      gload16(aA + k0 + (size_t)(8 * j) * 1024, &As[(32 * w + 8 * j) * 64]);
      gload16(aB + k0 + (size_t)(8 * j) * 1024, &Bs[(32 * w + 8 * j) * 64]);
    }
    __syncthreads();   // barrier drains vmcnt: tiles resident
#pragma unroll
    for (int kk = 0; kk < 64; kk += 32) {
      int sA = (((quad + (kk >> 3)) ^ (ln & 7))) * 8;
      bf16x8 af[4], bfr[4];
#pragma unroll
      for (int rt = 0; rt < 4; rt++)
        af[rt] = *(const bf16x8*)&As[(wr + 16 * rt + ln) * 64 + sA];
#pragma unroll
      for (int ct = 0; ct < 4; ct++)
        bfr[ct] = *(const bf16x8*)&Bs[(wc + 16 * ct + ln) * 64 + sA];
#pragma unroll
      for (int rt = 0; rt < 4; rt++)
#pragma unroll
        for (int ct = 0; ct < 4; ct++)
          acc[rt][ct] = mfma16(af[rt], bfr[ct], acc[rt][ct]);
    }
    __syncthreads();   // reads done before next-step staging overwrites
  }

  gemm_epilogue(acc, bias, bscale, Cv, layout, m0, n0, wr, wc, quad, ln);
}

// ---- legacy 128x128x64 GEMM with f32 A staged through VGPR pack ------------
__device__ __forceinline__ void gemm128_body_f32(
    const float* __restrict__ Av, const u16* __restrict__ Bt,
    const float* __restrict__ bias, float bscale, void* __restrict__ Cv,
    int layout) {
  __shared__ __align__(16) u16 As[128][72];
  __shared__ __align__(16) u16 Bs[128][72];
  int m0 = blockIdx.x * 128, n0 = blockIdx.y * 128;
  int tid = threadIdx.x;
  int w = tid >> 6, lane = tid & 63, quad = lane >> 4, ln = lane & 15;
  int wr = (w >> 1) * 64, wc = (w & 1) * 64;
  int sr = tid >> 1, seg = (tid & 1) * 32;

  f32x4 acc[4][4];
#pragma unroll
  for (int i = 0; i < 4; i++)
#pragma unroll
    for (int j = 0; j < 4; j++) { acc[i][j][0]=0.f; acc[i][j][1]=0.f; acc[i][j][2]=0.f; acc[i][j][3]=0.f; }

  for (int k0 = 0; k0 < 1024; k0 += 64) {
    {
      const float* ap = Av + (size_t)(m0 + sr) * 1024 + k0 + seg;
      u32 pk[16];
#pragma unroll
      for (int j = 0; j < 8; j++) {
        f32x4 v = *(const f32x4*)(ap + 4 * j);
        pk[2 * j]     = pack2(v[0], v[1]);
        pk[2 * j + 1] = pack2(v[2], v[3]);
      }
      u32* d = (u32*)&As[sr][seg];
#pragma unroll
      for (int j = 0; j < 4; j++) *(u32x4*)(d + 4 * j) = *(u32x4*)(pk + 4 * j);
    }
    {
      const u16* bp = Bt + (size_t)(n0 + sr) * 1024 + k0 + seg;
#pragma unroll
      for (int j = 0; j < 4; j++)
        *(bf16x8*)&Bs[sr][seg + 8 * j] = *(const bf16x8*)(bp + 8 * j);
    }
    __syncthreads();
#pragma unroll
    for (int kk = 0; kk < 64; kk += 32) {
      bf16x8 af[4], bfr[4];
#pragma unroll
      for (int rt = 0; rt < 4; rt++)
        af[rt] = *(const bf16x8*)&As[wr + 16 * rt + ln][kk + quad * 8];
#pragma unroll
      for (int ct = 0; ct < 4; ct++)
        bfr[ct] = *(const bf16x8*)&Bs[wc + 16 * ct + ln][kk + quad * 8];
#pragma unroll
      for (int rt = 0; rt < 4; rt++)
#pragma unroll
        for (int ct = 0; ct < 4; ct++)
          acc[rt][ct] = mfma16(af[rt], bfr[ct], acc[rt][ct]);
    }
    __syncthreads();
  }

  gemm_epilogue(acc, bias, bscale, Cv, layout, m0, n0, wr, wc, quad, ln);
}

// f32-A variant (fallback path)
__global__ __launch_bounds__(256) void gemm_qkv_f32(
    const float* q, const float* k, const float* v, const u16* WT,
    const float* bq, const float* bk, const float* bv,
    u16* Qp, u16* Kp, u16* Vt) {
  int z = blockIdx.z;
  const float* A = (z == 0) ? q : (z == 1) ? k : v;
  const u16* Bt = WT + (size_t)z * (1024 * 1024);
  const float* bias = (z == 0) ? bq : (z == 1) ? bk : bv;
  float bscale = (z == 0) ? QSCALE : 1.0f;
  void* C = (z == 0) ? (void*)Qp : (z == 1) ? (void*)Kp : (void*)Vt;
  gemm128_body_f32(A, Bt, bias, bscale, C, (z == 2) ? 2 : 1);
}

// bf16-A variant (fast path: q/k/v pre-converted; global_load_lds staging)
__global__ __launch_bounds__(256) void gemm_qkv_bf(
    const u16* qb, const u16* kb, const u16* vb, const u16* WT,
    const float* bq, const float* bk, const float* bv,
    u16* Qp, u16* Kp, u16* Vt) {
  int z = blockIdx.z;
  const u16* A = (z == 0) ? qb : (z == 1) ? kb : vb;
  const u16* Bt = WT + (size_t)z * (1024 * 1024);
  const float* bias = (z == 0) ? bq : (z == 1) ? bk : bv;
  float bscale = (z == 0) ? QSCALE : 1.0f;
  void* C = (z == 0) ? (void*)Qp : (z == 1) ? (void*)Kp : (void*)Vt;
  gemm_glds_body(A, Bt, bias, bscale, C, (z == 2) ? 2 : 1);
}

__global__ __launch_bounds__(256) void gemm_out(
    const u16* A, const u16* Bt, const float* bias, float* C) {
  gemm_glds_body(A, Bt, bias, 1.0f, C, 0);
}

// ---- flash causal attention, 256-k super-iterations, register rel-band -----
// Only lP remains in LDS (35840 B -> 4 blocks/CU, all 1024 blocks resident).
// Band math: slot needed at (ii=row0+r, jj=16c+ln) of tile t is
//   s_local = 16*(4t+c) + Kq_r + ln,  Kq_r = 15-4quad-r,
// relative to borig = R0f+js+48-16w. Generator group m covers s_local in
// [16m,16m+16); producer rotates (ds_bpermute within quad-16) and resolves
// the carry (Kq_r+ln>=16) via select against the previous group -> packed
// column-aligned regs Bp[4t+c] (compile-time index; bf16 pairs, same
// precision as the old LDS round-trip).
#define PSTRIDE 280   // u16 row stride; 256 cols used; rows 16B-aligned

__global__ __launch_bounds__(256, 4) void attn_v2(
    const u16* __restrict__ Q, const u16* __restrict__ K,
    const u16* __restrict__ Vt, const u16* __restrict__ RB,
    u16* __restrict__ att) {
  __shared__ __align__(16) u16 lP[64 * PSTRIDE];   // P tile, 256 cols used

  int bh = blockIdx.x;
  int qt = 15 - blockIdx.y;                        // heavy tiles first
  int b = bh >> 4, h = bh & 15;
  int tid = threadIdx.x;
  int w = tid >> 6, lane = tid & 63, quad = lane >> 4, ln = lane & 15;

  const u16* Qb = Q + (size_t)bh * 65536;
  const u16* Kb = K + (size_t)bh * 65536;
  const u16* Vb = Vt + (size_t)bh * 65536;
  const u16* Rb = RB + h * 64;                     // row stride 1024

  int row0 = 16 * w + quad * 4;                    // C-layout row base
  int i0 = qt * 64;
  int R0f = 960 - i0;

  // loop-invariant rotation controls (per r): source lane + carry cond
  int vaddr[4];
  bool cond[4];
#pragma unroll
  for (int r = 0; r < 4; r++) {
    int Kq = 15 - 4 * quad - r;
    vaddr[r] = (((lane & 48) | ((Kq + ln) & 15))) << 2;
    cond[r] = (Kq + ln) >= 16;
  }

  int qrow = i0 + 16 * w + ln;
  bf16x8 qa0 = *(const bf16x8*)(Qb + (size_t)qrow * 64 + quad * 8);
  bf16x8 qa1 = *(const bf16x8*)(Qb + (size_t)qrow * 64 + 32 + quad * 8);

  bf16x8 ones;
#pragma unroll
  for (int i = 0; i < 8; i++) ones[i] = (short)0x3F80;  // bf16 1.0

  f32x4 o[4], lacc;
#pragma unroll
  for (int c = 0; c < 4; c++) { o[c][0]=0.f; o[c][1]=0.f; o[c][2]=0.f; o[c][3]=0.f; }
  lacc[0]=0.f; lacc[1]=0.f; lacc[2]=0.f; lacc[3]=0.f;

#pragma unroll 1
  for (int js = 0; js <= i0; js += 256) {
    int ntiles = ((i0 - js) >> 6) + 1;
    if (ntiles > 4) ntiles = 4;
    int borig = R0f + js + 48 - 16 * w;            // per-wave band origin
    int mtop = 4 * ntiles;                         // groups m = 0..mtop

    // ---- rel band -> registers (rotated, carry-resolved, bf16-packed) ----
    u32 Bp[16][2];
    f32x4 prev;
    prev[0]=0.f; prev[1]=0.f; prev[2]=0.f; prev[3]=0.f;
#pragma unroll
    for (int m = 0; m <= 16; m++) {
      if (m <= mtop) {
        int rrow = borig + 16 * m + ln;
        int rl = rrow > 1023 ? 1023 : rrow;        // OOB rows only hit masked cols
        const u16* Rrow = Rb + (size_t)rl * 1024 + quad * 8;
        f32x4 a; a[0]=0.f; a[1]=0.f; a[2]=0.f; a[3]=0.f;
        a = mfma16(qa0, *(const bf16x8*)(Rrow), a);
        a = mfma16(qa1, *(const bf16x8*)(Rrow + 32), a);
        f32x4 rot;
#pragma unroll
        for (int r = 0; r < 4; r++) {
          int rv = __builtin_amdgcn_ds_bpermute(vaddr[r], (int)fbits(a[r]));
          rot[r] = uif((u32)rv);
        }
        if (m >= 1) {
          float b0 = cond[0] ? rot[0] : prev[0];
          float b1 = cond[1] ? rot[1] : prev[1];
          float b2 = cond[2] ? rot[2] : prev[2];
          float b3 = cond[3] ? rot[3] : prev[3];
          Bp[m - 1][0] = pack2(b0, b1);
          Bp[m - 1][1] = pack2(b2, b3);
        }
        prev = rot;
      }
    }

    // ---- 4 independent score-tile chains (band add is register-only) ----
#pragma unroll
    for (int t = 0; t < 4; t++) {
      if (t < ntiles) {
        int j0 = js + 64 * t;
        bf16x8 kf[4][2];
#pragma unroll
        for (int c = 0; c < 4; c++) {
          const u16* Krow = Kb + (size_t)(j0 + 16 * c + ln) * 64 + quad * 8;
          kf[c][0] = *(const bf16x8*)(Krow);
          kf[c][1] = *(const bf16x8*)(Krow + 32);
        }
        f32x4 sc[4];
#pragma unroll
        for (int c = 0; c < 4; c++) {
          f32x4 a; a[0]=0.f; a[1]=0.f; a[2]=0.f; a[3]=0.f;
          a = mfma16(qa0, kf[c][0], a);
          a = mfma16(qa1, kf[c][1], a);
          sc[c] = a;
        }
        bool diag = (j0 == i0);
#pragma unroll
        for (int c = 0; c < 4; c++) {
          u32 pk0 = Bp[4 * t + c][0];
          u32 pk1 = Bp[4 * t + c][1];
          int jj = 16 * c + ln;
#pragma unroll
          for (int r = 0; r < 4; r++) {
            u16 bv = (u16)((r == 0) ? pk0 : (r == 1) ? (pk0 >> 16)
                           : (r == 2) ? pk1 : (pk1 >> 16));
            float s = sc[c][r] + b2f(bv);
            int ii = row0 + r;
            float p = (diag && jj > ii) ? 0.f : exp2_fast(s);
            lP[ii * PSTRIDE + 64 * t + jj] = f2b(p);
          }
        }
      }
    }
    asm volatile("s_waitcnt lgkmcnt(0)" ::: "memory");  // P visible

    // ---- PV GEMM over 256 k (+ row sums via ones-B MFMA) ----
    int KC = 2 * ntiles;
#pragma unroll 1
    for (int kc = 0; kc < KC; kc++) {
      bf16x8 pa = *(const bf16x8*)&lP[(16 * w + ln) * PSTRIDE + 32 * kc + quad * 8];
      lacc = mfma16(pa, ones, lacc);
#pragma unroll
      for (int c = 0; c < 4; c++) {
        const u16* Vrow = Vb + (size_t)(16 * c + ln) * 1024 + js + 32 * kc + quad * 8;
        o[c] = mfma16(pa, *(const bf16x8*)(Vrow), o[c]);
      }
    }
    asm volatile("s_waitcnt lgkmcnt(0)" ::: "memory");  // WAR: reads done
  }

  // ---- epilogue: normalize, merge heads ----
#pragma unroll
  for (int c = 0; c < 4; c++) {
#pragma unroll
    for (int r = 0; r < 4; r++) {
      int i_abs = i0 + row0 + r;
      att[((size_t)(b * 1024 + i_abs)) * 1024 + h * 64 + 16 * c + ln] =
          f2b(o[c][r] / lacc[r]);
    }
  }
}

// ---------------------------------------------------------------------------
extern "C" void kernel_launch(void* const* d_in, const int* in_sizes, int n_in,
                              void* d_out, int out_size, void* d_ws, size_t ws_size,
                              hipStream_t stream) {
  const float* query = (const float*)d_in[0];
  const float* key   = (const float*)d_in[1];
  const float* value = (const float*)d_in[2];
  // d_in[3] = attention_mask (int32, triu k=1) -- causal, hardcoded in attn
  const float* Wq = (const float*)d_in[4];
  const float* bq = (const float*)d_in[5];
  const float* Wk = (const float*)d_in[6];
  const float* bk = (const float*)d_in[7];
  const float* Wv = (const float*)d_in[8];
  const float* bv = (const float*)d_in[9];
  const float* RT = (const float*)d_in[10];
  const float* Wo = (const float*)d_in[11];
  const float* bo = (const float*)d_in[12];
  float* out = (float*)d_out;

  const size_t EM = 1024 * 1024;     // elems of one 1024x1024 matrix
  u16* ws   = (u16*)d_ws;
  u16* WT   = ws;                    // [0,3EM): WqT, WkT, WvT
  u16* relb = ws + 3 * EM;           // [3EM,4EM)
  u16* Kp   = ws + 4 * EM;           // [4EM,8EM)
  u16* Vtp  = ws + 8 * EM;           // [8EM,12EM)
  u16* Qp   = (u16*)d_out;           // d_out scratch, front half
  u16* WoT  = ws;                    // over dead WT

  prep<<<dim3(16, 16, 4), 256, 0, stream>>>(Wq, Wk, Wv, RT,
                                            WT, WT + EM, WT + 2 * EM, relb);

  if (ws_size >= (size_t)48 * 1024 * 1024) {
    // fast path: pre-convert q/k/v to bf16; GEMMs stage via global_load_lds;
    // attn output goes over dead qb region (no memcpy needed)
    u16* qb = ws + 12 * EM;          // [12EM,16EM)
    u16* kb = ws + 16 * EM;          // [16EM,20EM)
    u16* vb = ws + 20 * EM;          // [20EM,24EM)
    cvt_qkv<<<dim3(4096, 3), 256, 0, stream>>>(query, key, value, qb, kb, vb);
    gemm_qkv_bf<<<dim3(32, 8, 3), 256, 0, stream>>>(qb, kb, vb, WT,
                                                    bq, bk, bv, Qp, Kp, Vtp);
    u16* attw = ws + 12 * EM;        // over dead qb
    attn_v2<<<dim3(64, 16), 256, 0, stream>>>(Qp, Kp, Vtp, relb, attw);
    transpose_wo<<<dim3(16, 16), 256, 0, stream>>>(Wo, WoT);
    gemm_out<<<dim3(32, 8), 256, 0, stream>>>(attw, WoT, bo, out);
  } else {
    gemm_qkv_f32<<<dim3(32, 8, 3), 256, 0, stream>>>(query, key, value, WT,
                                                     bq, bk, bv, Qp, Kp, Vtp);
    u16* attb = (u16*)d_out + 4 * EM;  // d_out scratch, back half
    u16* attc = ws + 4 * EM;           // att copy over dead Kp
    attn_v2<<<dim3(64, 16), 256, 0, stream>>>(Qp, Kp, Vtp, relb, attb);
    hipMemcpyAsync(attc, attb, 8 * 1024 * 1024, hipMemcpyDeviceToDevice, stream);
    transpose_wo<<<dim3(16, 16), 256, 0, stream>>>(Wo, WoT);
    gemm_out<<<dim3(32, 8), 256, 0, stream>>>(attc, WoT, bo, out);
  }
}

// Round 6
// 298.900 us; speedup vs baseline: 1.0371x; 1.0371x over previous
//
#include <hip/hip_runtime.h>
#include <cstddef>
#include <cstdint>

// ---------------------------------------------------------------------------
// MultiHeadRelativeAttention (music-transformer skew), B=4 H=16 S=1024 hd=64
// Inputs/outputs f32; internal bf16 MFMA.
// R15: fix R13's register-band spill (VGPR 64 + ~5MB excess WRITE = scratch).
// Band generation interleaved into the score-tile loop: group 0 as prologue,
// then groups 4t+1..4t+4 right before tile t's K-loads, chaining prev across
// tiles. Peak live band state Bp[16][2] -> Bp[4][2] (~20 fewer live regs).
// launch_bounds(256,3): VGPR cap ~170 (no spill), 3 blocks/CU via LDS 35840.
// Everything else identical to R13/R14 (which passed correctness).
// GEMMs: global_load_lds staging w/ XOR swizzle (R11). exp2, log2e in Wq/bq.
// Fast ws layout (u16 elems, EM=1M): WT[0,3) relb[3,4) Kp[4,8) Vt[8,12)
//   qb[12,16) kb[16,20) vb[20,24) = 48 MB. Post-attn: WoT over WT,
//   attn out over qb[12,16). d_out front half = Qp bf16 scratch.
// ---------------------------------------------------------------------------

typedef __attribute__((ext_vector_type(8))) short bf16x8;   // 8 bf16, 4 VGPRs
typedef __attribute__((ext_vector_type(4))) float f32x4;
typedef __attribute__((ext_vector_type(4))) unsigned int u32x4;

using u16 = unsigned short;
using u32 = unsigned int;

#define QSCALE (0.125f * 1.44269504089f)   // attn scale * log2(e), folded into Wq/bq

__device__ __forceinline__ f32x4 mfma16(bf16x8 a, bf16x8 b, f32x4 c) {
  return __builtin_amdgcn_mfma_f32_16x16x32_bf16(a, b, c, 0, 0, 0);
}
__device__ __forceinline__ u32 fbits(float f) {
  union { float f; u32 u; } v; v.f = f; return v.u;
}
__device__ __forceinline__ float uif(u32 u) {
  union { u32 u; float f; } v; v.u = u; return v.f;
}
// f32 -> bf16, round-half-up (tie bias negligible at this threshold)
__device__ __forceinline__ u16 f2b(float f) { return (u16)((fbits(f) + 0x8000u) >> 16); }
__device__ __forceinline__ u32 pack2(float a, float b) {
  return ((fbits(a) + 0x8000u) >> 16) | ((fbits(b) + 0x8000u) & 0xffff0000u);
}
__device__ __forceinline__ float b2f(u16 u) {
  union { u32 i; float f; } v; v.i = ((u32)u) << 16; return v.f;
}
// raw v_exp_f32 (input already in log2 domain; log2e folded into Wq)
__device__ __forceinline__ float exp2_fast(float x) {
  float r; asm("v_exp_f32 %0, %1" : "=v"(r) : "v"(x)); return r;
}
// async global->LDS, 16B per lane; LDS dest = uniform base + lane*16
__device__ __forceinline__ void gload16(const void* g, void* l) {
  __builtin_amdgcn_global_load_lds(
      (const __attribute__((address_space(1))) u32*)g,
      (__attribute__((address_space(3))) u32*)l, 16, 0, 0);
}

// ---- bulk f32 -> bf16 conversion of q,k,v ----------------------------------
__global__ __launch_bounds__(256) void cvt_qkv(
    const float* __restrict__ a0, const float* __restrict__ a1,
    const float* __restrict__ a2, u16* __restrict__ o0,
    u16* __restrict__ o1, u16* __restrict__ o2) {
  int z = blockIdx.y;
  const float* src = (z == 0) ? a0 : (z == 1) ? a1 : a2;
  u16* dst = (z == 0) ? o0 : (z == 1) ? o1 : o2;
  size_t i = ((size_t)blockIdx.x * 256 + threadIdx.x) * 4;
  f32x4 v = *(const f32x4*)(src + i);
  uint2 pk; pk.x = pack2(v[0], v[1]); pk.y = pack2(v[2], v[3]);
  *(uint2*)(dst + i) = pk;
}

// ---- prep: z=0..2 transpose Wq/Wk/Wv (f32 -> bf16^T, Wq pre-scaled by
//      0.125*log2e); z=3 convert rel_tab f32 -> bf16 -------------------------
__global__ __launch_bounds__(256) void prep(
    const float* __restrict__ Wq, const float* __restrict__ Wk,
    const float* __restrict__ Wv, const float* __restrict__ rel,
    u16* __restrict__ WqT, u16* __restrict__ WkT, u16* __restrict__ WvT,
    u16* __restrict__ relb) {
  __shared__ __align__(16) u16 tile[64][65];
  int z = blockIdx.z;
  if (z == 3) {
    int blk = blockIdx.y * 16 + blockIdx.x;
    size_t base = (size_t)blk * 4096;
#pragma unroll
    for (int e = 0; e < 4; e++) {
      size_t idx = base + e * 1024 + threadIdx.x * 4;
      f32x4 v = *(const f32x4*)(rel + idx);
      uint2 pk; pk.x = pack2(v[0], v[1]); pk.y = pack2(v[2], v[3]);
      *(uint2*)(relb + idx) = pk;
    }
    return;
  }
  const float* W = (z == 0) ? Wq : (z == 1) ? Wk : Wv;
  u16* T = (z == 0) ? WqT : (z == 1) ? WkT : WvT;
  float sc = (z == 0) ? QSCALE : 1.0f;   // fold attn scale + log2e into Wq
  int k0 = blockIdx.x * 64, n0 = blockIdx.y * 64;
  for (int e = threadIdx.x; e < 4096; e += 256) {
    int r = e >> 6, c = e & 63;
    tile[r][c] = f2b(sc * W[(size_t)(k0 + r) * 1024 + n0 + c]);
  }
  __syncthreads();
  for (int e = threadIdx.x; e < 4096; e += 256) {
    int r = e >> 6, c = e & 63;
    T[(size_t)(n0 + r) * 1024 + k0 + c] = tile[c][r];
  }
}

// ---- transpose Wo (f32 -> bf16^T), after attn, into dead WT region ---------
__global__ __launch_bounds__(256) void transpose_wo(
    const float* __restrict__ W, u16* __restrict__ T) {
  __shared__ __align__(16) u16 tile[64][65];
  int k0 = blockIdx.x * 64, n0 = blockIdx.y * 64;
  for (int e = threadIdx.x; e < 4096; e += 256) {
    int r = e >> 6, c = e & 63;
    tile[r][c] = f2b(W[(size_t)(k0 + r) * 1024 + n0 + c]);
  }
  __syncthreads();
  for (int e = threadIdx.x; e < 4096; e += 256) {
    int r = e >> 6, c = e & 63;
    T[(size_t)(n0 + r) * 1024 + k0 + c] = tile[c][r];
  }
}

// ---- shared epilogue: acc -> C with bias, 3 layouts ------------------------
__device__ __forceinline__ void gemm_epilogue(
    f32x4 (&acc)[4][4], const float* __restrict__ bias, float bscale,
    void* __restrict__ Cv, int layout, int m0, int n0, int wr, int wc,
    int quad, int ln) {
#pragma unroll
  for (int ct = 0; ct < 4; ct++) {
    int n = n0 + wc + 16 * ct + ln;
    float bs = bscale * bias[n];
#pragma unroll
    for (int rt = 0; rt < 4; rt++) {
#pragma unroll
      for (int r = 0; r < 4; r++) {
        int m = m0 + wr + 16 * rt + quad * 4 + r;
        float v = acc[rt][ct][r] + bs;
        if (layout == 0) {
          ((float*)Cv)[(size_t)m * 1024 + n] = v;
        } else {
          int b_ = m >> 10, s = m & 1023, h = n >> 6, d = n & 63;
          size_t idx = (layout == 1)
              ? ((size_t)(b_ * 16 + h) * 1024 + s) * 64 + d
              : ((size_t)(b_ * 16 + h) * 64 + d) * 1024 + s;
          ((u16*)Cv)[idx] = f2b(v);
        }
      }
    }
  }
}

// ---- 128x128x(BK=64) GEMM, bf16 A/B staged via global_load_lds -------------
// LDS tiles are LINEAR [128][64] (gload_lds needs contiguous dest).
// Swizzle: LDS[R][8p] holds A[R][8(p ^ (R&7))]; realized by pre-swizzling the
// per-lane SOURCE column, and reading with sA = 8*((quad+(kk>>3)) ^ (ln&7)).
// Each 8-lane group then covers all 8 bank slots -> conflict-free b128 reads.
__device__ __forceinline__ void gemm_glds_body(
    const u16* __restrict__ A, const u16* __restrict__ Bt,
    const float* __restrict__ bias, float bscale, void* __restrict__ Cv,
    int layout) {
  __shared__ __align__(16) u16 As[128 * 64];
  __shared__ __align__(16) u16 Bs[128 * 64];
  int m0 = blockIdx.x * 128, n0 = blockIdx.y * 128;
  int tid = threadIdx.x;
  int w = tid >> 6, lane = tid & 63, quad = lane >> 4, ln = lane & 15;
  int wr = (w >> 1) * 64, wc = (w & 1) * 64;     // wave quadrant origin

  // staging: each wave stages 32 rows of A and B per K-step (4 instrs each);
  // lane -> row 32w+8j+(lane>>3), source col pre-swizzled
  int rowin = lane >> 3;                         // 0..7
  int swz = ((lane & 7) ^ rowin) * 8;            // u16 col offset in row

  f32x4 acc[4][4];
#pragma unroll
  for (int i = 0; i < 4; i++)
#pragma unroll
    for (int j = 0; j < 4; j++) { acc[i][j][0]=0.f; acc[i][j][1]=0.f; acc[i][j][2]=0.f; acc[i][j][3]=0.f; }

  const u16* aA = A  + (size_t)(m0 + 32 * w + rowin) * 1024 + swz;
  const u16* aB = Bt + (size_t)(n0 + 32 * w + rowin) * 1024 + swz;

  for (int k0 = 0; k0 < 1024; k0 += 64) {
#pragma unroll
    for (int j = 0; j < 4; j++) {
      gload16(aA + k0 + (size_t)(8 * j) * 1024, &As[(32 * w + 8 * j) * 64]);
      gload16(aB + k0 + (size_t)(8 * j) * 1024, &Bs[(32 * w + 8 * j) * 64]);
    }
    __syncthreads();   // barrier drains vmcnt: tiles resident
#pragma unroll
    for (int kk = 0; kk < 64; kk += 32) {
      int sA = (((quad + (kk >> 3)) ^ (ln & 7))) * 8;
      bf16x8 af[4], bfr[4];
#pragma unroll
      for (int rt = 0; rt < 4; rt++)
        af[rt] = *(const bf16x8*)&As[(wr + 16 * rt + ln) * 64 + sA];
#pragma unroll
      for (int ct = 0; ct < 4; ct++)
        bfr[ct] = *(const bf16x8*)&Bs[(wc + 16 * ct + ln) * 64 + sA];
#pragma unroll
      for (int rt = 0; rt < 4; rt++)
#pragma unroll
        for (int ct = 0; ct < 4; ct++)
          acc[rt][ct] = mfma16(af[rt], bfr[ct], acc[rt][ct]);
    }
    __syncthreads();   // reads done before next-step staging overwrites
  }

  gemm_epilogue(acc, bias, bscale, Cv, layout, m0, n0, wr, wc, quad, ln);
}

// ---- legacy 128x128x64 GEMM with f32 A staged through VGPR pack ------------
__device__ __forceinline__ void gemm128_body_f32(
    const float* __restrict__ Av, const u16* __restrict__ Bt,
    const float* __restrict__ bias, float bscale, void* __restrict__ Cv,
    int layout) {
  __shared__ __align__(16) u16 As[128][72];
  __shared__ __align__(16) u16 Bs[128][72];
  int m0 = blockIdx.x * 128, n0 = blockIdx.y * 128;
  int tid = threadIdx.x;
  int w = tid >> 6, lane = tid & 63, quad = lane >> 4, ln = lane & 15;
  int wr = (w >> 1) * 64, wc = (w & 1) * 64;
  int sr = tid >> 1, seg = (tid & 1) * 32;

  f32x4 acc[4][4];
#pragma unroll
  for (int i = 0; i < 4; i++)
#pragma unroll
    for (int j = 0; j < 4; j++) { acc[i][j][0]=0.f; acc[i][j][1]=0.f; acc[i][j][2]=0.f; acc[i][j][3]=0.f; }

  for (int k0 = 0; k0 < 1024; k0 += 64) {
    {
      const float* ap = Av + (size_t)(m0 + sr) * 1024 + k0 + seg;
      u32 pk[16];
#pragma unroll
      for (int j = 0; j < 8; j++) {
        f32x4 v = *(const f32x4*)(ap + 4 * j);
        pk[2 * j]     = pack2(v[0], v[1]);
        pk[2 * j + 1] = pack2(v[2], v[3]);
      }
      u32* d = (u32*)&As[sr][seg];
#pragma unroll
      for (int j = 0; j < 4; j++) *(u32x4*)(d + 4 * j) = *(u32x4*)(pk + 4 * j);
    }
    {
      const u16* bp = Bt + (size_t)(n0 + sr) * 1024 + k0 + seg;
#pragma unroll
      for (int j = 0; j < 4; j++)
        *(bf16x8*)&Bs[sr][seg + 8 * j] = *(const bf16x8*)(bp + 8 * j);
    }
    __syncthreads();
#pragma unroll
    for (int kk = 0; kk < 64; kk += 32) {
      bf16x8 af[4], bfr[4];
#pragma unroll
      for (int rt = 0; rt < 4; rt++)
        af[rt] = *(const bf16x8*)&As[wr + 16 * rt + ln][kk + quad * 8];
#pragma unroll
      for (int ct = 0; ct < 4; ct++)
        bfr[ct] = *(const bf16x8*)&Bs[wc + 16 * ct + ln][kk + quad * 8];
#pragma unroll
      for (int rt = 0; rt < 4; rt++)
#pragma unroll
        for (int ct = 0; ct < 4; ct++)
          acc[rt][ct] = mfma16(af[rt], bfr[ct], acc[rt][ct]);
    }
    __syncthreads();
  }

  gemm_epilogue(acc, bias, bscale, Cv, layout, m0, n0, wr, wc, quad, ln);
}

// f32-A variant (fallback path)
__global__ __launch_bounds__(256) void gemm_qkv_f32(
    const float* q, const float* k, const float* v, const u16* WT,
    const float* bq, const float* bk, const float* bv,
    u16* Qp, u16* Kp, u16* Vt) {
  int z = blockIdx.z;
  const float* A = (z == 0) ? q : (z == 1) ? k : v;
  const u16* Bt = WT + (size_t)z * (1024 * 1024);
  const float* bias = (z == 0) ? bq : (z == 1) ? bk : bv;
  float bscale = (z == 0) ? QSCALE : 1.0f;
  void* C = (z == 0) ? (void*)Qp : (z == 1) ? (void*)Kp : (void*)Vt;
  gemm128_body_f32(A, Bt, bias, bscale, C, (z == 2) ? 2 : 1);
}

// bf16-A variant (fast path: q/k/v pre-converted; global_load_lds staging)
__global__ __launch_bounds__(256) void gemm_qkv_bf(
    const u16* qb, const u16* kb, const u16* vb, const u16* WT,
    const float* bq, const float* bk, const float* bv,
    u16* Qp, u16* Kp, u16* Vt) {
  int z = blockIdx.z;
  const u16* A = (z == 0) ? qb : (z == 1) ? kb : vb;
  const u16* Bt = WT + (size_t)z * (1024 * 1024);
  const float* bias = (z == 0) ? bq : (z == 1) ? bk : bv;
  float bscale = (z == 0) ? QSCALE : 1.0f;
  void* C = (z == 0) ? (void*)Qp : (z == 1) ? (void*)Kp : (void*)Vt;
  gemm_glds_body(A, Bt, bias, bscale, C, (z == 2) ? 2 : 1);
}

__global__ __launch_bounds__(256) void gemm_out(
    const u16* A, const u16* Bt, const float* bias, float* C) {
  gemm_glds_body(A, Bt, bias, 1.0f, C, 0);
}

// ---- flash causal attention, 256-k super-iterations, register rel-band -----
// Only lP remains in LDS (35840 B). Band slot needed at (ii=row0+r,
// jj=16c+ln) of tile t is s_local = 16*(4t+c) + Kq_r + ln, Kq_r = 15-4quad-r,
// relative to borig = R0f+js+48-16w. Bp[4t+c] = cond ? rot(group 4t+c+1)
//                                              : rot(group 4t+c).
// R15: groups generated interleaved -- group 0 as prologue, then groups
// 4t+1..4t+4 immediately before tile t's K-loads, chaining prev. Peak live
// band state = prev + rot + Bp[4][2] (was Bp[16][2] -> spilled in R14).
#define PSTRIDE 280   // u16 row stride; 256 cols used; rows 16B-aligned

__global__ __launch_bounds__(256, 3) void attn_v2(
    const u16* __restrict__ Q, const u16* __restrict__ K,
    const u16* __restrict__ Vt, const u16* __restrict__ RB,
    u16* __restrict__ att) {
  __shared__ __align__(16) u16 lP[64 * PSTRIDE];   // P tile, 256 cols used

  int bh = blockIdx.x;
  int qt = 15 - blockIdx.y;                        // heavy tiles first
  int b = bh >> 4, h = bh & 15;
  int tid = threadIdx.x;
  int w = tid >> 6, lane = tid & 63, quad = lane >> 4, ln = lane & 15;

  const u16* Qb = Q + (size_t)bh * 65536;
  const u16* Kb = K + (size_t)bh * 65536;
  const u16* Vb = Vt + (size_t)bh * 65536;
  const u16* Rb = RB + h * 64;                     // row stride 1024

  int row0 = 16 * w + quad * 4;                    // C-layout row base
  int i0 = qt * 64;
  int R0f = 960 - i0;

  // loop-invariant rotation controls (per r): source lane + carry cond
  int vaddr[4];
  bool cond[4];
#pragma unroll
  for (int r = 0; r < 4; r++) {
    int Kq = 15 - 4 * quad - r;
    vaddr[r] = (((lane & 48) | ((Kq + ln) & 15))) << 2;
    cond[r] = (Kq + ln) >= 16;
  }

  int qrow = i0 + 16 * w + ln;
  bf16x8 qa0 = *(const bf16x8*)(Qb + (size_t)qrow * 64 + quad * 8);
  bf16x8 qa1 = *(const bf16x8*)(Qb + (size_t)qrow * 64 + 32 + quad * 8);

  bf16x8 ones;
#pragma unroll
  for (int i = 0; i < 8; i++) ones[i] = (short)0x3F80;  // bf16 1.0

  f32x4 o[4], lacc;
#pragma unroll
  for (int c = 0; c < 4; c++) { o[c][0]=0.f; o[c][1]=0.f; o[c][2]=0.f; o[c][3]=0.f; }
  lacc[0]=0.f; lacc[1]=0.f; lacc[2]=0.f; lacc[3]=0.f;

#pragma unroll 1
  for (int js = 0; js <= i0; js += 256) {
    int ntiles = ((i0 - js) >> 6) + 1;
    if (ntiles > 4) ntiles = 4;
    int borig = R0f + js + 48 - 16 * w;            // per-wave band origin

    // ---- prologue: band group 0 -> prev ----
    f32x4 prev;
    {
      int rrow = borig + ln;
      int rl = rrow > 1023 ? 1023 : rrow;          // OOB rows only hit masked cols
      const u16* Rrow = Rb + (size_t)rl * 1024 + quad * 8;
      f32x4 a; a[0]=0.f; a[1]=0.f; a[2]=0.f; a[3]=0.f;
      a = mfma16(qa0, *(const bf16x8*)(Rrow), a);
      a = mfma16(qa1, *(const bf16x8*)(Rrow + 32), a);
#pragma unroll
      for (int r = 0; r < 4; r++)
        prev[r] = uif((u32)__builtin_amdgcn_ds_bpermute(vaddr[r], (int)fbits(a[r])));
    }

    // ---- 4 score-tile chains; band groups generated just-in-time ----
#pragma unroll
    for (int t = 0; t < 4; t++) {
      if (t < ntiles) {
        // band groups 4t+1..4t+4 -> Bp[0..3] (chained via prev)
        u32 Bp[4][2];
#pragma unroll
        for (int u = 0; u < 4; u++) {
          int m = 4 * t + 1 + u;
          int rrow = borig + 16 * m + ln;
          int rl = rrow > 1023 ? 1023 : rrow;
          const u16* Rrow = Rb + (size_t)rl * 1024 + quad * 8;
          f32x4 a; a[0]=0.f; a[1]=0.f; a[2]=0.f; a[3]=0.f;
          a = mfma16(qa0, *(const bf16x8*)(Rrow), a);
          a = mfma16(qa1, *(const bf16x8*)(Rrow + 32), a);
          f32x4 rot;
#pragma unroll
          for (int r = 0; r < 4; r++)
            rot[r] = uif((u32)__builtin_amdgcn_ds_bpermute(vaddr[r], (int)fbits(a[r])));
          float b0 = cond[0] ? rot[0] : prev[0];
          float b1 = cond[1] ? rot[1] : prev[1];
          float b2 = cond[2] ? rot[2] : prev[2];
          float b3 = cond[3] ? rot[3] : prev[3];
          Bp[u][0] = pack2(b0, b1);
          Bp[u][1] = pack2(b2, b3);
          prev = rot;
        }

        int j0 = js + 64 * t;
        bf16x8 kf[4][2];
#pragma unroll
        for (int c = 0; c < 4; c++) {
          const u16* Krow = Kb + (size_t)(j0 + 16 * c + ln) * 64 + quad * 8;
          kf[c][0] = *(const bf16x8*)(Krow);
          kf[c][1] = *(const bf16x8*)(Krow + 32);
        }
        f32x4 sc[4];
#pragma unroll
        for (int c = 0; c < 4; c++) {
          f32x4 a; a[0]=0.f; a[1]=0.f; a[2]=0.f; a[3]=0.f;
          a = mfma16(qa0, kf[c][0], a);
          a = mfma16(qa1, kf[c][1], a);
          sc[c] = a;
        }
        bool diag = (j0 == i0);
#pragma unroll
        for (int c = 0; c < 4; c++) {
          u32 pk0 = Bp[c][0];
          u32 pk1 = Bp[c][1];
          int jj = 16 * c + ln;
#pragma unroll
          for (int r = 0; r < 4; r++) {
            u16 bv = (u16)((r == 0) ? pk0 : (r == 1) ? (pk0 >> 16)
                           : (r == 2) ? pk1 : (pk1 >> 16));
            float s = sc[c][r] + b2f(bv);
            int ii = row0 + r;
            float p = (diag && jj > ii) ? 0.f : exp2_fast(s);
            lP[ii * PSTRIDE + 64 * t + jj] = f2b(p);
          }
        }
      }
    }
    asm volatile("s_waitcnt lgkmcnt(0)" ::: "memory");  // P visible

    // ---- PV GEMM over 256 k (+ row sums via ones-B MFMA) ----
    int KC = 2 * ntiles;
#pragma unroll 1
    for (int kc = 0; kc < KC; kc++) {
      bf16x8 pa = *(const bf16x8*)&lP[(16 * w + ln) * PSTRIDE + 32 * kc + quad * 8];
      lacc = mfma16(pa, ones, lacc);
#pragma unroll
      for (int c = 0; c < 4; c++) {
        const u16* Vrow = Vb + (size_t)(16 * c + ln) * 1024 + js + 32 * kc + quad * 8;
        o[c] = mfma16(pa, *(const bf16x8*)(Vrow), o[c]);
      }
    }
    asm volatile("s_waitcnt lgkmcnt(0)" ::: "memory");  // WAR: reads done
  }

  // ---- epilogue: normalize, merge heads ----
#pragma unroll
  for (int c = 0; c < 4; c++) {
#pragma unroll
    for (int r = 0; r < 4; r++) {
      int i_abs = i0 + row0 + r;
      att[((size_t)(b * 1024 + i_abs)) * 1024 + h * 64 + 16 * c + ln] =
          f2b(o[c][r] / lacc[r]);
    }
  }
}

// ---------------------------------------------------------------------------
extern "C" void kernel_launch(void* const* d_in, const int* in_sizes, int n_in,
                              void* d_out, int out_size, void* d_ws, size_t ws_size,
                              hipStream_t stream) {
  const float* query = (const float*)d_in[0];
  const float* key   = (const float*)d_in[1];
  const float* value = (const float*)d_in[2];
  // d_in[3] = attention_mask (int32, triu k=1) -- causal, hardcoded in attn
  const float* Wq = (const float*)d_in[4];
  const float* bq = (const float*)d_in[5];
  const float* Wk = (const float*)d_in[6];
  const float* bk = (const float*)d_in[7];
  const float* Wv = (const float*)d_in[8];
  const float* bv = (const float*)d_in[9];
  const float* RT = (const float*)d_in[10];
  const float* Wo = (const float*)d_in[11];
  const float* bo = (const float*)d_in[12];
  float* out = (float*)d_out;

  const size_t EM = 1024 * 1024;     // elems of one 1024x1024 matrix
  u16* ws   = (u16*)d_ws;
  u16* WT   = ws;                    // [0,3EM): WqT, WkT, WvT
  u16* relb = ws + 3 * EM;           // [3EM,4EM)
  u16* Kp   = ws + 4 * EM;           // [4EM,8EM)
  u16* Vtp  = ws + 8 * EM;           // [8EM,12EM)
  u16* Qp   = (u16*)d_out;           // d_out scratch, front half
  u16* WoT  = ws;                    // over dead WT

  prep<<<dim3(16, 16, 4), 256, 0, stream>>>(Wq, Wk, Wv, RT,
                                            WT, WT + EM, WT + 2 * EM, relb);

  if (ws_size >= (size_t)48 * 1024 * 1024) {
    // fast path: pre-convert q/k/v to bf16; GEMMs stage via global_load_lds;
    // attn output goes over dead qb region (no memcpy needed)
    u16* qb = ws + 12 * EM;          // [12EM,16EM)
    u16* kb = ws + 16 * EM;          // [16EM,20EM)
    u16* vb = ws + 20 * EM;          // [20EM,24EM)
    cvt_qkv<<<dim3(4096, 3), 256, 0, stream>>>(query, key, value, qb, kb, vb);
    gemm_qkv_bf<<<dim3(32, 8, 3), 256, 0, stream>>>(qb, kb, vb, WT,
                                                    bq, bk, bv, Qp, Kp, Vtp);
    u16* attw = ws + 12 * EM;        // over dead qb
    attn_v2<<<dim3(64, 16), 256, 0, stream>>>(Qp, Kp, Vtp, relb, attw);
    transpose_wo<<<dim3(16, 16), 256, 0, stream>>>(Wo, WoT);
    gemm_out<<<dim3(32, 8), 256, 0, stream>>>(attw, WoT, bo, out);
  } else {
    gemm_qkv_f32<<<dim3(32, 8, 3), 256, 0, stream>>>(query, key, value, WT,
                                                     bq, bk, bv, Qp, Kp, Vtp);
    u16* attb = (u16*)d_out + 4 * EM;  // d_out scratch, back half
    u16* attc = ws + 4 * EM;           // att copy over dead Kp
    attn_v2<<<dim3(64, 16), 256, 0, stream>>>(Qp, Kp, Vtp, relb, attb);
    hipMemcpyAsync(attc, attb, 8 * 1024 * 1024, hipMemcpyDeviceToDevice, stream);
    transpose_wo<<<dim3(16, 16), 256, 0, stream>>>(Wo, WoT);
    gemm_out<<<dim3(32, 8), 256, 0, stream>>>(attc, WoT, bo, out);
  }
}